// Round 9
// baseline (734.573 us; speedup 1.0000x reference)
//
#include <hip/hip_runtime.h>
#include <stdint.h>

#define EPSF 1e-7f
#define MAXTAN 10.0f

typedef __bf16 bf16x8 __attribute__((ext_vector_type(8)));
typedef float floatx4 __attribute__((ext_vector_type(4)));
typedef __attribute__((address_space(3))) void lds_void_t;
typedef __attribute__((address_space(1))) void gbl_void_t;

__device__ __forceinline__ unsigned short f2bf(float x) {
  union { float f; uint32_t u; } v; v.f = x;
  uint32_t u = v.u;
  u += 0x7fffu + ((u >> 16) & 1u);   // RNE
  return (unsigned short)(u >> 16);
}
__device__ __forceinline__ float bf2f(unsigned short h) {
  union { uint32_t u; float f; } v; v.u = ((uint32_t)h) << 16;
  return v.f;
}

__device__ __forceinline__ int sniff_mode(const unsigned short* x) {
  int sane = 0;
  for (int i = 0; i < 128; ++i) {
    unsigned short h = x[i];
    int e = (h >> 7) & 0xFF;
    if ((h & 0x7FFF) == 0 || (e >= 96 && e <= 140)) ++sane;
  }
  return (sane >= 120) ? 1 : 0;
}

// ---------------- init: sniff dtype + convert biases ----------------
__global__ void k_init(const unsigned short* __restrict__ x, int* __restrict__ modeg,
                       const void* __restrict__ b1, const void* __restrict__ b2,
                       const void* __restrict__ b3, float* __restrict__ o1,
                       float* __restrict__ o2, float* __restrict__ o3) {
  __shared__ int mds;
  if (threadIdx.x == 0) {
    int m = sniff_mode(x);
    mds = m;
    if (blockIdx.x == 0) *modeg = m;
  }
  __syncthreads();
  int m = mds;
  int i = blockIdx.x * 256 + threadIdx.x;
  if (i < 4096) o1[i] = m ? bf2f(((const unsigned short*)b1)[i]) : ((const float*)b1)[i];
  if (i < 4096) o2[i] = m ? bf2f(((const unsigned short*)b2)[i]) : ((const float*)b2)[i];
  if (i < 1024) o3[i] = m ? bf2f(((const unsigned short*)b3)[i]) : ((const float*)b3)[i];
}

// ---------------- x prep: convert to bf16, compute logmap scale + x0 ----------------
__global__ void k_prep(const void* __restrict__ xv, unsigned short* __restrict__ xb,
                       float* __restrict__ sc0, float* __restrict__ x0c,
                       const int* __restrict__ mode) {
  const int row = blockIdx.x;
  const int tid = threadIdx.x;
  float4 v;
  if (*mode) {
    ushort4 u = ((const ushort4*)((const unsigned short*)xv + (size_t)row * 1024))[tid];
    v.x = bf2f(u.x); v.y = bf2f(u.y); v.z = bf2f(u.z); v.w = bf2f(u.w);
  } else {
    v = ((const float4*)((const float*)xv + (size_t)row * 1024))[tid];
  }
  ushort4 o;
  o.x = f2bf(v.x); o.y = f2bf(v.y); o.z = f2bf(v.z); o.w = f2bf(v.w);
  ((ushort4*)(xb + (size_t)row * 1024))[tid] = o;

  float s = v.x * v.x + v.y * v.y + v.z * v.z + v.w * v.w;
  if (tid == 0) s -= v.x * v.x;          // exclude time coordinate
  for (int off = 32; off; off >>= 1) s += __shfl_down(s, off, 64);
  __shared__ float red[4];
  if ((tid & 63) == 0) red[tid >> 6] = s;
  __syncthreads();
  if (tid == 0) {
    s = red[0] + red[1] + red[2] + red[3];
    float ns = fmaxf(sqrtf(s), EPSF);
    float d = acoshf(fmaxf(v.x, 1.0f + EPSF));
    sc0[row] = d / ns;
    x0c[row] = bf2f(o.x);
  }
}

// ---------------- weight convert to bf16 + col0 extraction ----------------
template<int K8>
__global__ void k_cvtw(const void* __restrict__ in, unsigned short* __restrict__ out,
                       const int* __restrict__ mode, int n8, float* __restrict__ c0) {
  int i = blockIdx.x * 256 + threadIdx.x;
  if (i >= n8) return;
  if (*mode) {
    uint4 g = ((const uint4*)in)[i];
    ((uint4*)out)[i] = g;
    if (i % K8 == 0) c0[i / K8] = bf2f((unsigned short)(g.x & 0xFFFFu));
  } else {
    float4 a = ((const float4*)in)[2 * i];
    float4 b = ((const float4*)in)[2 * i + 1];
    ushort4 oa, ob;
    oa.x = f2bf(a.x); oa.y = f2bf(a.y); oa.z = f2bf(a.z); oa.w = f2bf(a.w);
    ob.x = f2bf(b.x); ob.y = f2bf(b.y); ob.z = f2bf(b.z); ob.w = f2bf(b.w);
    ((ushort4*)out)[2 * i] = oa;
    ((ushort4*)out)[2 * i + 1] = ob;
    if (i % K8 == 0) c0[i / K8] = bf2f(oa.x);
  }
}

// ---------------- partial-sumsq fold -> scale + col0 grab ----------------
template<int NBLK>
__global__ void k_sc(const float* __restrict__ part, const unsigned short* __restrict__ y,
                     int stride, float* __restrict__ sc, float* __restrict__ c0,
                     float* __restrict__ ssout, int nrows) {
  int i = blockIdx.x * 256 + threadIdx.x;
  if (i >= nrows) return;
  float s = 0.f;
#pragma unroll
  for (int j = 0; j < NBLK; ++j) s += part[(size_t)i * NBLK + j];
  float n = fmaxf(sqrtf(fmaxf(s, 0.f)), EPSF);
  sc[i] = fminf(n, MAXTAN) / n;
  c0[i] = bf2f(y[(size_t)i * stride]);
  if (ssout) ssout[i] = s;
}

// ---------------- final: y3 bf16 + ss3 -> projx(safe_expmap0(y3)) ----------------
__global__ void k_final(const unsigned short* __restrict__ y, const float* __restrict__ ss,
                        void* __restrict__ outv, const int* __restrict__ mode) {
  const int row = blockIdx.x;
  const int tid = threadIdx.x;
  float n = fmaxf(sqrtf(fmaxf(ss[row], 0.f)), EPSF);
  float nc = fminf(n, MAXTAN);
  float a = sinhf(nc) / n;
  ushort4 u = ((const ushort4*)(y + (size_t)row * 1024))[tid];
  float4 o;
  o.x = bf2f(u.x) * a; o.y = bf2f(u.y) * a;
  o.z = bf2f(u.z) * a; o.w = bf2f(u.w) * a;
  if (tid == 0) o.x = coshf(nc);
  if (*mode) {
    ushort4 o16;
    o16.x = f2bf(o.x); o16.y = f2bf(o.y); o16.z = f2bf(o.z); o16.w = f2bf(o.w);
    ((ushort4*)outv)[(size_t)row * 256 + tid] = o16;
  } else {
    ((float4*)outv)[(size_t)row * 256 + tid] = o;
  }
}

// ---------------- legacy 128x128 NT GEMM (kept for GEMM3) ----------------
template<int N, int K, int NBLK, int GX>
__global__ __launch_bounds__(256, 4) void k_gemm_bt(
    const unsigned short* __restrict__ A,
    const unsigned short* __restrict__ B,
    const float* __restrict__ bias,
    const float* __restrict__ sc,
    const float* __restrict__ c0f,
    const float* __restrict__ wc0,
    unsigned short* __restrict__ Cb,
    float* __restrict__ part)
{
  __shared__ __align__(16) unsigned short As[128 * 32];
  __shared__ __align__(16) unsigned short Bs[128 * 32];

  const int tid  = threadIdx.x;
  const int wave = tid >> 6;
  const int lane = tid & 63;
  const int quad = lane >> 4;
  const int m16  = lane & 15;

  const int j = blockIdx.x & 7;
  const int k = blockIdx.x >> 3;
  int bxi, byi;
  if (GX == 32) {
    bxi = 16 * (j & 1) + (k & 15);
    byi = 16 * (j >> 1) + (k >> 4);
  } else {
    bxi = k & 7;
    byi = 8 * j + (k >> 3);
  }
  const int bm = byi * 128;
  const int bn = bxi * 128;

  const int srow = lane >> 2;
  const int scol = (((lane & 3) ^ ((srow >> 1) & 3)) << 3);

  const int wm = (wave >> 1) << 6;
  const int wn = (wave & 1) << 6;

  const int rsw = ((quad ^ ((m16 >> 1) & 3)) << 3);

  const int c0i = wave * 2;
  const unsigned short* ga0 = A + (size_t)(bm + c0i * 16 + srow) * K + scol;
  const unsigned short* ga1 = ga0 + (size_t)16 * K;
  const unsigned short* gb0 = B + (size_t)(bn + c0i * 16 + srow) * K + scol;
  const unsigned short* gb1 = gb0 + (size_t)16 * K;

  floatx4 acc[4][4];
#pragma unroll
  for (int i = 0; i < 4; ++i)
#pragma unroll
    for (int jj = 0; jj < 4; ++jj)
#pragma unroll
      for (int r = 0; r < 4; ++r) acc[i][jj][r] = 0.0f;

  for (int k0 = 0; k0 < K; k0 += 32) {
    __builtin_amdgcn_global_load_lds((gbl_void_t*)(void*)ga0,
                                     (lds_void_t*)(As + c0i * 512), 16, 0, 0);
    __builtin_amdgcn_global_load_lds((gbl_void_t*)(void*)ga1,
                                     (lds_void_t*)(As + c0i * 512 + 512), 16, 0, 0);
    __builtin_amdgcn_global_load_lds((gbl_void_t*)(void*)gb0,
                                     (lds_void_t*)(Bs + c0i * 512), 16, 0, 0);
    __builtin_amdgcn_global_load_lds((gbl_void_t*)(void*)gb1,
                                     (lds_void_t*)(Bs + c0i * 512 + 512), 16, 0, 0);
    ga0 += 32; ga1 += 32; gb0 += 32; gb1 += 32;
    __syncthreads();

    bf16x8 af[4], bfg[4];
#pragma unroll
    for (int t = 0; t < 4; ++t) {
      af[t]  = *(const bf16x8*)(As + (wm + t * 16 + m16) * 32 + rsw);
      bfg[t] = *(const bf16x8*)(Bs + (wn + t * 16 + m16) * 32 + rsw);
    }
#pragma unroll
    for (int mt = 0; mt < 4; ++mt)
#pragma unroll
      for (int nt = 0; nt < 4; ++nt)
        acc[mt][nt] = __builtin_amdgcn_mfma_f32_16x16x32_bf16(af[mt], bfg[nt], acc[mt][nt], 0, 0, 0);
    __syncthreads();
  }

#pragma unroll
  for (int mt = 0; mt < 4; ++mt) {
#pragma unroll
    for (int r = 0; r < 4; ++r) {
      const int gm = bm + wm + mt * 16 + quad * 4 + r;
      const float scv = sc[gm];
      const float c0v = c0f[gm];
      float sq = 0.f;
#pragma unroll
      for (int nt = 0; nt < 4; ++nt) {
        const int gn = bn + wn + nt * 16 + m16;
        float v = scv * (acc[mt][nt][r] - c0v * wc0[gn]) + bias[gn];
        Cb[(size_t)gm * N + gn] = f2bf(v);
        sq += (gn == 0) ? 0.f : v * v;
      }
      sq += __shfl_xor(sq, 1, 64);
      sq += __shfl_xor(sq, 2, 64);
      sq += __shfl_xor(sq, 4, 64);
      sq += __shfl_xor(sq, 8, 64);
      if (m16 == 0) part[(size_t)gm * NBLK + 2 * bxi + (wave & 1)] = sq;
    }
  }
}

// ---------------- 256x256 NT GEMM: A via LDS, B direct global->reg (R9) ----------------
// R3-R8 established: schedule variants all pin MfmaUtil at 47-53% because LDS traffic
//   (96KB ds_read + 32KB GLL-write per K32-step per block ~= 1400 cyc/CU) rivals the
//   MFMA demand (1190 cyc). R9 removes B from LDS entirely:
// B-frag algebra (stage swz ^ read swz cancel): lane(quad,m16), wave wc, frag nt reads
//   EXACTLY global B[bn + wc*64 + nt*16 + m16][T*32 + quad*8 .. +7] -- one contiguous
//   16B dwordx4 per lane, loaded straight to VGPRs, prefetched one K-tile ahead.
//   B-panel is reused by 32 M-blocks -> L2-hot. LDS now A-only: 64KB reads + 16KB
//   writes ~= 900 cyc < 1190 MFMA -> matrix pipe becomes the binding resource.
// Structure = R6 skeleton: 512 thr / 8 waves (2M x 4N), per-wave 128x64, acc[8][4];
//   A 4-slot ring 4x16KB = 64KB LDS; x4-unrolled main loop (compile-time slots),
//   peeled 4-body tail; same granule swizzle (0 conflicts) and epilogue.
// Per body BI (tile T=t+BI): {4x B-load(T+1) -> 2x GLL A(T+3) -> 8x ds_read a(T) ->
//   32 MFMA (setprio) -> asm vmcnt(2) -> s_barrier}.
// vmcnt ledger (6 VMEM ops/iter: 4 B then 2 GLL): end-of-iter-T vmcnt(2) leaves only
//   GLL(T+3) in flight => B(T+1) landed (next iter's operands) and GLL(T+2) landed
//   (slot (T+2)&3 resident one iter early). Residency for iter T+1 reads (slot
//   (T+1)&3): staged iter T-2, landed by end of iter T-1. WAR: GLL(T+3) writes slot
//   (T-1)&3 whose readers finished before iter T-1's barrier. Prologue: [B(0)x4,
//   GLL t0,t1,t2] vmcnt(4) -> B(0)+tile0 landed. Tail (base t=NT-4): STG(3,96)=tile
//   NT-1; TB0 (slot0, consume bX=B(NT-4), load bY=B(NT-3)); vmcnt(0)+barrier (drains
//   GLL NT-2,NT-1); TB1..TB3 barrier-free (B loads L2-hot, compiler auto-waits).
// Epilogue: y = sc[m]*(acc - c0f[m]*wc0[n]) + bias[n]; partials part[gm*64 + bxi*4 + wc].
template<int N, int K>
__global__ __launch_bounds__(512, 2) void k_gemm256(
    const unsigned short* __restrict__ A,
    const unsigned short* __restrict__ B,
    const float* __restrict__ bias,
    const float* __restrict__ sc,
    const float* __restrict__ c0f,
    const float* __restrict__ wc0,
    unsigned short* __restrict__ Cb,
    float* __restrict__ part)
{
  static_assert(K % 128 == 0 && K / 32 >= 8, "need NT multiple of 4, >= 8");
  constexpr int NT = K / 32;
  __shared__ __align__(16) unsigned short S[4][8192];   // A-only: [slot][256 x 32]

  const int tid  = threadIdx.x;
  const int wave = tid >> 6;
  const int lane = tid & 63;
  const int quad = lane >> 4;
  const int m16  = lane & 15;
  const int wr   = wave >> 2;     // 0..1 (M half)
  const int wc   = wave & 3;      // 0..3 (N column)

  // bijective XCD swizzle: 512 blocks = 8 XCDs x 64; each XCD gets an 8x8 tile patch
  const int j = blockIdx.x & 7;
  const int k = blockIdx.x >> 3;                 // 0..63
  const int bxi = 8 * (j & 1) + (k & 7);         // 0..15  (N/256)
  const int byi = 8 * (j >> 1) + (k >> 3);       // 0..31  (M/256)
  const int bm = byi * 256;
  const int bn = bxi * 256;

  // A staging: thread -> row tid>>2, LDS granule tid&3; global granule pre-swizzled
  const int gsw8 = (((tid & 3) ^ ((tid >> 3) & 3)) << 3);
  const unsigned short* gAp = A + (size_t)(bm + (tid >> 2)) * K + gsw8;   // rows 0..127
  const unsigned short* gAq = gAp + (size_t)128 * K;                      // rows 128..255
  char* SbW = (char*)&S[0][0];
  const int ldw = wave * 1024;     // wave's 16-row stripe within an 8KB half-region

  // B direct-load lane pointers: row = bn + wc*64 + nt*16 + m16, col granule = quad*8
  const unsigned short* pB0 = B + (size_t)(bn + wc * 64 + m16) * K + quad * 8;
  const unsigned short* pB1 = pB0 + (size_t)16 * K;
  const unsigned short* pB2 = pB0 + (size_t)32 * K;
  const unsigned short* pB3 = pB0 + (size_t)48 * K;

  // A read side: swizzled granule, byte base + compile-time slot/frag immediates
  const int rsw8 = ((quad ^ ((m16 >> 1) & 3)) << 3);
  const char* Ab = (const char*)&S[0][0] + ((wr * 128 + m16) * 32 + rsw8) * 2;

  floatx4 acc[8][4];
#pragma unroll
  for (int i = 0; i < 8; ++i)
#pragma unroll
    for (int jj = 0; jj < 4; ++jj)
#pragma unroll
      for (int r = 0; r < 4; ++r) acc[i][jj][r] = 0.0f;

#define GLL(SRC, DST) __builtin_amdgcn_global_load_lds((gbl_void_t*)(void*)(SRC), (lds_void_t*)(DST), 16, 0, 0)
#define STG(SL, CO) { GLL(gAp + (CO), SbW + (SL) * 16384 + ldw); \
                      GLL(gAq + (CO), SbW + (SL) * 16384 + 8192 + ldw); }
#define LDB(BN, CO) { BN[0] = *(const bf16x8*)(pB0 + (CO)); \
                      BN[1] = *(const bf16x8*)(pB1 + (CO)); \
                      BN[2] = *(const bf16x8*)(pB2 + (CO)); \
                      BN[3] = *(const bf16x8*)(pB3 + (CO)); }
#define ARD(SL, M_) (*(const bf16x8*)(Ab + (SL) * 16384 + (M_) * 1024))

  // prologue: B(0) + stage A tiles 0,1,2; vmcnt(4) -> B(0) and tile 0 landed
  bf16x8 bX[4], bY[4];
  LDB(bX, 0)
  STG(0, 0) STG(1, 32) STG(2, 64)
  asm volatile("s_waitcnt vmcnt(4)" ::: "memory");
  __builtin_amdgcn_s_barrier();

  // main body BI (0..3): tile T=t+BI from slot BI; load B(T+1); stage A(T+3)
#define MBODY(BI, BC, BN)                                                              \
  {                                                                                    \
    LDB(BN, (BI + 1) * 32)                                                             \
    STG((BI + 3) & 3, (BI + 3) * 32)                                                   \
    bf16x8 a_[8];                                                                      \
    _Pragma("unroll")                                                                  \
    for (int m = 0; m < 8; ++m) a_[m] = ARD(BI, m);                                    \
    __builtin_amdgcn_s_setprio(1);                                                     \
    _Pragma("unroll")                                                                  \
    for (int f = 0; f < 8; ++f)                                                        \
      _Pragma("unroll")                                                                \
      for (int n = 0; n < 4; ++n)                                                      \
        acc[f][n] = __builtin_amdgcn_mfma_f32_16x16x32_bf16(a_[f], BC[n], acc[f][n], 0, 0, 0); \
    __builtin_amdgcn_s_setprio(0);                                                     \
    asm volatile("s_waitcnt vmcnt(2)" ::: "memory");                                   \
    __builtin_amdgcn_s_barrier();                                                      \
  }

  for (int t = 0; t < NT - 4; t += 4) {
    MBODY(0, bX, bY)
    MBODY(1, bY, bX)
    MBODY(2, bX, bY)
    MBODY(3, bY, bX)
    gAp += 128; gAq += 128; pB0 += 128; pB1 += 128; pB2 += 128; pB3 += 128;
  }
  // after loop: bX = B(NT-4); pointers at tile NT-4's column; slots 0..3 = NT-4..NT-1

  // tail: stage tile NT-1 (slot 3)
  STG(3, 96)
  // TB0 (tile NT-4, slot 0): consume bX, load bY = B(NT-3)
  {
    LDB(bY, 32)
    bf16x8 a_[8];
#pragma unroll
    for (int m = 0; m < 8; ++m) a_[m] = ARD(0, m);
    __builtin_amdgcn_s_setprio(1);
#pragma unroll
    for (int f = 0; f < 8; ++f)
#pragma unroll
      for (int n = 0; n < 4; ++n)
        acc[f][n] = __builtin_amdgcn_mfma_f32_16x16x32_bf16(a_[f], bX[n], acc[f][n], 0, 0, 0);
    __builtin_amdgcn_s_setprio(0);
  }
  // drain all staging (tiles NT-2, NT-1) block-wide
  asm volatile("s_waitcnt vmcnt(0)" ::: "memory");
  __builtin_amdgcn_s_barrier();
  // TB1 (tile NT-3, slot 1): consume bY, load bX = B(NT-2)
  {
    LDB(bX, 64)
    bf16x8 a_[8];
#pragma unroll
    for (int m = 0; m < 8; ++m) a_[m] = ARD(1, m);
    __builtin_amdgcn_s_setprio(1);
#pragma unroll
    for (int f = 0; f < 8; ++f)
#pragma unroll
      for (int n = 0; n < 4; ++n)
        acc[f][n] = __builtin_amdgcn_mfma_f32_16x16x32_bf16(a_[f], bY[n], acc[f][n], 0, 0, 0);
    __builtin_amdgcn_s_setprio(0);
  }
  // TB2 (tile NT-2, slot 2): consume bX, load bY = B(NT-1)
  {
    LDB(bY, 96)
    bf16x8 a_[8];
#pragma unroll
    for (int m = 0; m < 8; ++m) a_[m] = ARD(2, m);
    __builtin_amdgcn_s_setprio(1);
#pragma unroll
    for (int f = 0; f < 8; ++f)
#pragma unroll
      for (int n = 0; n < 4; ++n)
        acc[f][n] = __builtin_amdgcn_mfma_f32_16x16x32_bf16(a_[f], bX[n], acc[f][n], 0, 0, 0);
    __builtin_amdgcn_s_setprio(0);
  }
  // TB3 (tile NT-1, slot 3): consume bY
  {
    bf16x8 a_[8];
#pragma unroll
    for (int m = 0; m < 8; ++m) a_[m] = ARD(3, m);
    __builtin_amdgcn_s_setprio(1);
#pragma unroll
    for (int f = 0; f < 8; ++f)
#pragma unroll
      for (int n = 0; n < 4; ++n)
        acc[f][n] = __builtin_amdgcn_mfma_f32_16x16x32_bf16(a_[f], bY[n], acc[f][n], 0, 0, 0);
    __builtin_amdgcn_s_setprio(0);
  }

#undef MBODY
#undef ARD
#undef LDB
#undef STG
#undef GLL

  // epilogue: C/D layout col = lane&15, row = quad*4 + r
  const int wm = wr * 128;
  const int wn = wc * 64;
#pragma unroll
  for (int mt = 0; mt < 8; ++mt) {
#pragma unroll
    for (int r = 0; r < 4; ++r) {
      const int gm = bm + wm + mt * 16 + quad * 4 + r;
      const float scv = sc[gm];
      const float c0v = c0f[gm];
      float sq = 0.f;
#pragma unroll
      for (int nt = 0; nt < 4; ++nt) {
        const int gn = bn + wn + nt * 16 + m16;
        float v = scv * (acc[mt][nt][r] - c0v * wc0[gn]) + bias[gn];
        Cb[(size_t)gm * N + gn] = f2bf(v);
        sq += (gn == 0) ? 0.f : v * v;
      }
      sq += __shfl_xor(sq, 1, 64);
      sq += __shfl_xor(sq, 2, 64);
      sq += __shfl_xor(sq, 4, 64);
      sq += __shfl_xor(sq, 8, 64);
      if (m16 == 0) part[(size_t)gm * 64 + bxi * 4 + wc] = sq;
    }
  }
}

extern "C" void kernel_launch(void* const* d_in, const int* in_sizes, int n_in,
                              void* d_out, int out_size, void* d_ws, size_t ws_size,
                              hipStream_t stream) {
  const void* x  = d_in[0];
  const void* W1 = d_in[1];
  const void* b1 = d_in[2];
  const void* W2 = d_in[3];
  const void* b2 = d_in[4];
  const void* W3 = d_in[5];
  const void* b3 = d_in[6];

  const int NR = 8192, DIN = 1024, DH = 4096, DOUT = 1024;

  char* ws = (char*)d_ws;
  size_t off = 0;
  int* mode = (int*)(ws + off);                        off += 256;
  unsigned short* W1b = (unsigned short*)(ws + off);   off += (size_t)DH * DIN * 2;
  unsigned short* W2b = (unsigned short*)(ws + off);   off += (size_t)DH * DH * 2;
  unsigned short* W3b = (unsigned short*)(ws + off);   off += (size_t)DOUT * DH * 2;
  unsigned short* xb  = (unsigned short*)(ws + off);   off += (size_t)NR * DIN * 2;
  unsigned short* y1  = (unsigned short*)(ws + off);   off += (size_t)NR * DH * 2;
  unsigned short* y2  = (unsigned short*)(ws + off);   off += (size_t)NR * DH * 2;
  unsigned short* y3  = (unsigned short*)(ws + off);   off += (size_t)NR * DOUT * 2;
  float* part1 = (float*)(ws + off);                   off += (size_t)NR * 64 * 4;
  float* part2 = (float*)(ws + off);                   off += (size_t)NR * 64 * 4;
  float* part3 = (float*)(ws + off);                   off += (size_t)NR * 16 * 4;
  float* sc0  = (float*)(ws + off);                    off += (size_t)NR * 4;
  float* x0c  = (float*)(ws + off);                    off += (size_t)NR * 4;
  float* sc1  = (float*)(ws + off);                    off += (size_t)NR * 4;
  float* c01  = (float*)(ws + off);                    off += (size_t)NR * 4;
  float* sc2  = (float*)(ws + off);                    off += (size_t)NR * 4;
  float* c02  = (float*)(ws + off);                    off += (size_t)NR * 4;
  float* ss3  = (float*)(ws + off);                    off += (size_t)NR * 4;
  float* w1c0 = (float*)(ws + off);                    off += (size_t)DH * 4;
  float* w2c0 = (float*)(ws + off);                    off += (size_t)DH * 4;
  float* w3c0 = (float*)(ws + off);                    off += (size_t)DOUT * 4;
  float* b1f  = (float*)(ws + off);                    off += (size_t)DH * 4;
  float* b2f  = (float*)(ws + off);                    off += (size_t)DH * 4;
  float* b3f  = (float*)(ws + off);                    off += (size_t)DOUT * 4;

  k_init<<<16, 256, 0, stream>>>((const unsigned short*)x, mode, b1, b2, b3, b1f, b2f, b3f);

  k_cvtw<128><<<(DH * DIN / 8 + 255) / 256, 256, 0, stream>>>(W1, W1b, mode, DH * DIN / 8, w1c0);
  k_cvtw<512><<<(DH * DH  / 8 + 255) / 256, 256, 0, stream>>>(W2, W2b, mode, DH * DH / 8, w2c0);
  k_cvtw<512><<<(DOUT * DH / 8 + 255) / 256, 256, 0, stream>>>(W3, W3b, mode, DOUT * DH / 8, w3c0);

  k_prep<<<NR, 256, 0, stream>>>(x, xb, sc0, x0c, mode);

  k_gemm256<4096, 1024><<<512, 512, 0, stream>>>(
      xb, W1b, b1f, sc0, x0c, w1c0, y1, part1);
  k_sc<64><<<(NR + 255) / 256, 256, 0, stream>>>(part1, y1, DH, sc1, c01, nullptr, NR);

  k_gemm256<4096, 4096><<<512, 512, 0, stream>>>(
      y1, W2b, b2f, sc1, c01, w2c0, y2, part2);
  k_sc<64><<<(NR + 255) / 256, 256, 0, stream>>>(part2, y2, DH, sc2, c02, nullptr, NR);

  k_gemm_bt<1024, 4096, 16, 8><<<512, 256, 0, stream>>>(
      y2, W3b, b3f, sc2, c02, w3c0, y3, part3);
  k_sc<16><<<(NR + 255) / 256, 256, 0, stream>>>(part3, y3, DOUT, sc0, x0c, ss3, NR);

  k_final<<<NR, 256, 0, stream>>>(y3, ss3, d_out, mode);
}

// Round 10
// 727.461 us; speedup vs baseline: 1.0098x; 1.0098x over previous
//
#include <hip/hip_runtime.h>
#include <stdint.h>

#define EPSF 1e-7f
#define MAXTAN 10.0f

typedef __bf16 bf16x8 __attribute__((ext_vector_type(8)));
typedef float floatx4 __attribute__((ext_vector_type(4)));
typedef __attribute__((address_space(3))) void lds_void_t;
typedef __attribute__((address_space(1))) void gbl_void_t;

__device__ __forceinline__ unsigned short f2bf(float x) {
  union { float f; uint32_t u; } v; v.f = x;
  uint32_t u = v.u;
  u += 0x7fffu + ((u >> 16) & 1u);   // RNE
  return (unsigned short)(u >> 16);
}
__device__ __forceinline__ float bf2f(unsigned short h) {
  union { uint32_t u; float f; } v; v.u = ((uint32_t)h) << 16;
  return v.f;
}

__device__ __forceinline__ int sniff_mode(const unsigned short* x) {
  int sane = 0;
  for (int i = 0; i < 128; ++i) {
    unsigned short h = x[i];
    int e = (h >> 7) & 0xFF;
    if ((h & 0x7FFF) == 0 || (e >= 96 && e <= 140)) ++sane;
  }
  return (sane >= 120) ? 1 : 0;
}

// ---------------- init: sniff dtype + convert biases ----------------
__global__ void k_init(const unsigned short* __restrict__ x, int* __restrict__ modeg,
                       const void* __restrict__ b1, const void* __restrict__ b2,
                       const void* __restrict__ b3, float* __restrict__ o1,
                       float* __restrict__ o2, float* __restrict__ o3) {
  __shared__ int mds;
  if (threadIdx.x == 0) {
    int m = sniff_mode(x);
    mds = m;
    if (blockIdx.x == 0) *modeg = m;
  }
  __syncthreads();
  int m = mds;
  int i = blockIdx.x * 256 + threadIdx.x;
  if (i < 4096) o1[i] = m ? bf2f(((const unsigned short*)b1)[i]) : ((const float*)b1)[i];
  if (i < 4096) o2[i] = m ? bf2f(((const unsigned short*)b2)[i]) : ((const float*)b2)[i];
  if (i < 1024) o3[i] = m ? bf2f(((const unsigned short*)b3)[i]) : ((const float*)b3)[i];
}

// ---------------- x prep: convert to bf16, compute logmap scale + x0 ----------------
__global__ void k_prep(const void* __restrict__ xv, unsigned short* __restrict__ xb,
                       float* __restrict__ sc0, float* __restrict__ x0c,
                       const int* __restrict__ mode) {
  const int row = blockIdx.x;
  const int tid = threadIdx.x;
  float4 v;
  if (*mode) {
    ushort4 u = ((const ushort4*)((const unsigned short*)xv + (size_t)row * 1024))[tid];
    v.x = bf2f(u.x); v.y = bf2f(u.y); v.z = bf2f(u.z); v.w = bf2f(u.w);
  } else {
    v = ((const float4*)((const float*)xv + (size_t)row * 1024))[tid];
  }
  ushort4 o;
  o.x = f2bf(v.x); o.y = f2bf(v.y); o.z = f2bf(v.z); o.w = f2bf(v.w);
  ((ushort4*)(xb + (size_t)row * 1024))[tid] = o;

  float s = v.x * v.x + v.y * v.y + v.z * v.z + v.w * v.w;
  if (tid == 0) s -= v.x * v.x;          // exclude time coordinate
  for (int off = 32; off; off >>= 1) s += __shfl_down(s, off, 64);
  __shared__ float red[4];
  if ((tid & 63) == 0) red[tid >> 6] = s;
  __syncthreads();
  if (tid == 0) {
    s = red[0] + red[1] + red[2] + red[3];
    float ns = fmaxf(sqrtf(s), EPSF);
    float d = acoshf(fmaxf(v.x, 1.0f + EPSF));
    sc0[row] = d / ns;
    x0c[row] = bf2f(o.x);
  }
}

// ---------------- weight convert to bf16 + col0 extraction ----------------
template<int K8>
__global__ void k_cvtw(const void* __restrict__ in, unsigned short* __restrict__ out,
                       const int* __restrict__ mode, int n8, float* __restrict__ c0) {
  int i = blockIdx.x * 256 + threadIdx.x;
  if (i >= n8) return;
  if (*mode) {
    uint4 g = ((const uint4*)in)[i];
    ((uint4*)out)[i] = g;
    if (i % K8 == 0) c0[i / K8] = bf2f((unsigned short)(g.x & 0xFFFFu));
  } else {
    float4 a = ((const float4*)in)[2 * i];
    float4 b = ((const float4*)in)[2 * i + 1];
    ushort4 oa, ob;
    oa.x = f2bf(a.x); oa.y = f2bf(a.y); oa.z = f2bf(a.z); oa.w = f2bf(a.w);
    ob.x = f2bf(b.x); ob.y = f2bf(b.y); ob.z = f2bf(b.z); ob.w = f2bf(b.w);
    ((ushort4*)out)[2 * i] = oa;
    ((ushort4*)out)[2 * i + 1] = ob;
    if (i % K8 == 0) c0[i / K8] = bf2f(oa.x);
  }
}

// ---------------- partial-sumsq fold -> scale + col0 grab ----------------
template<int NBLK>
__global__ void k_sc(const float* __restrict__ part, const unsigned short* __restrict__ y,
                     int stride, float* __restrict__ sc, float* __restrict__ c0,
                     float* __restrict__ ssout, int nrows) {
  int i = blockIdx.x * 256 + threadIdx.x;
  if (i >= nrows) return;
  float s = 0.f;
#pragma unroll
  for (int j = 0; j < NBLK; ++j) s += part[(size_t)i * NBLK + j];
  float n = fmaxf(sqrtf(fmaxf(s, 0.f)), EPSF);
  sc[i] = fminf(n, MAXTAN) / n;
  c0[i] = bf2f(y[(size_t)i * stride]);
  if (ssout) ssout[i] = s;
}

// ---------------- final: y3 bf16 + ss3 -> projx(safe_expmap0(y3)) ----------------
__global__ void k_final(const unsigned short* __restrict__ y, const float* __restrict__ ss,
                        void* __restrict__ outv, const int* __restrict__ mode) {
  const int row = blockIdx.x;
  const int tid = threadIdx.x;
  float n = fmaxf(sqrtf(fmaxf(ss[row], 0.f)), EPSF);
  float nc = fminf(n, MAXTAN);
  float a = sinhf(nc) / n;
  ushort4 u = ((const ushort4*)(y + (size_t)row * 1024))[tid];
  float4 o;
  o.x = bf2f(u.x) * a; o.y = bf2f(u.y) * a;
  o.z = bf2f(u.z) * a; o.w = bf2f(u.w) * a;
  if (tid == 0) o.x = coshf(nc);
  if (*mode) {
    ushort4 o16;
    o16.x = f2bf(o.x); o16.y = f2bf(o.y); o16.z = f2bf(o.z); o16.w = f2bf(o.w);
    ((ushort4*)outv)[(size_t)row * 256 + tid] = o16;
  } else {
    ((float4*)outv)[(size_t)row * 256 + tid] = o;
  }
}

// ---------------- legacy 128x128 NT GEMM (kept for GEMM3) ----------------
template<int N, int K, int NBLK, int GX>
__global__ __launch_bounds__(256, 4) void k_gemm_bt(
    const unsigned short* __restrict__ A,
    const unsigned short* __restrict__ B,
    const float* __restrict__ bias,
    const float* __restrict__ sc,
    const float* __restrict__ c0f,
    const float* __restrict__ wc0,
    unsigned short* __restrict__ Cb,
    float* __restrict__ part)
{
  __shared__ __align__(16) unsigned short As[128 * 32];
  __shared__ __align__(16) unsigned short Bs[128 * 32];

  const int tid  = threadIdx.x;
  const int wave = tid >> 6;
  const int lane = tid & 63;
  const int quad = lane >> 4;
  const int m16  = lane & 15;

  const int j = blockIdx.x & 7;
  const int k = blockIdx.x >> 3;
  int bxi, byi;
  if (GX == 32) {
    bxi = 16 * (j & 1) + (k & 15);
    byi = 16 * (j >> 1) + (k >> 4);
  } else {
    bxi = k & 7;
    byi = 8 * j + (k >> 3);
  }
  const int bm = byi * 128;
  const int bn = bxi * 128;

  const int srow = lane >> 2;
  const int scol = (((lane & 3) ^ ((srow >> 1) & 3)) << 3);

  const int wm = (wave >> 1) << 6;
  const int wn = (wave & 1) << 6;

  const int rsw = ((quad ^ ((m16 >> 1) & 3)) << 3);

  const int c0i = wave * 2;
  const unsigned short* ga0 = A + (size_t)(bm + c0i * 16 + srow) * K + scol;
  const unsigned short* ga1 = ga0 + (size_t)16 * K;
  const unsigned short* gb0 = B + (size_t)(bn + c0i * 16 + srow) * K + scol;
  const unsigned short* gb1 = gb0 + (size_t)16 * K;

  floatx4 acc[4][4];
#pragma unroll
  for (int i = 0; i < 4; ++i)
#pragma unroll
    for (int jj = 0; jj < 4; ++jj)
#pragma unroll
      for (int r = 0; r < 4; ++r) acc[i][jj][r] = 0.0f;

  for (int k0 = 0; k0 < K; k0 += 32) {
    __builtin_amdgcn_global_load_lds((gbl_void_t*)(void*)ga0,
                                     (lds_void_t*)(As + c0i * 512), 16, 0, 0);
    __builtin_amdgcn_global_load_lds((gbl_void_t*)(void*)ga1,
                                     (lds_void_t*)(As + c0i * 512 + 512), 16, 0, 0);
    __builtin_amdgcn_global_load_lds((gbl_void_t*)(void*)gb0,
                                     (lds_void_t*)(Bs + c0i * 512), 16, 0, 0);
    __builtin_amdgcn_global_load_lds((gbl_void_t*)(void*)gb1,
                                     (lds_void_t*)(Bs + c0i * 512 + 512), 16, 0, 0);
    ga0 += 32; ga1 += 32; gb0 += 32; gb1 += 32;
    __syncthreads();

    bf16x8 af[4], bfg[4];
#pragma unroll
    for (int t = 0; t < 4; ++t) {
      af[t]  = *(const bf16x8*)(As + (wm + t * 16 + m16) * 32 + rsw);
      bfg[t] = *(const bf16x8*)(Bs + (wn + t * 16 + m16) * 32 + rsw);
    }
#pragma unroll
    for (int mt = 0; mt < 4; ++mt)
#pragma unroll
      for (int nt = 0; nt < 4; ++nt)
        acc[mt][nt] = __builtin_amdgcn_mfma_f32_16x16x32_bf16(af[mt], bfg[nt], acc[mt][nt], 0, 0, 0);
    __syncthreads();
  }

#pragma unroll
  for (int mt = 0; mt < 4; ++mt) {
#pragma unroll
    for (int r = 0; r < 4; ++r) {
      const int gm = bm + wm + mt * 16 + quad * 4 + r;
      const float scv = sc[gm];
      const float c0v = c0f[gm];
      float sq = 0.f;
#pragma unroll
      for (int nt = 0; nt < 4; ++nt) {
        const int gn = bn + wn + nt * 16 + m16;
        float v = scv * (acc[mt][nt][r] - c0v * wc0[gn]) + bias[gn];
        Cb[(size_t)gm * N + gn] = f2bf(v);
        sq += (gn == 0) ? 0.f : v * v;
      }
      sq += __shfl_xor(sq, 1, 64);
      sq += __shfl_xor(sq, 2, 64);
      sq += __shfl_xor(sq, 4, 64);
      sq += __shfl_xor(sq, 8, 64);
      if (m16 == 0) part[(size_t)gm * NBLK + 2 * bxi + (wave & 1)] = sq;
    }
  }
}

// ---------------- 256x256 NT GEMM: A via LDS, B direct global->reg (R10) ----------------
// R9 (this structure with vmcnt(2)) cratered to 29% MfmaUtil: per-iter VMEM order is
//   [LDB(T+1)x4, GLL(T+3)x2]; vmcnt(2) kept only GLL(T+3) -> forced GLL(T+2) (issued
//   ~1.2 iters earlier, HBM ~900+cyc) to land EVERY iter -> exposed HBM latency stall
//   (VALUBusy 11%, all pipes idle). R10 fix: fence = vmcnt(8), keeping
//   [GLL(T+2)^2, LDB(T+1)^4, GLL(T+3)^2] in flight -> A-stages get 2.2 iters of
//   latency slack; B(T+1) is guarded by the compiler's implicit wait before its
//   consuming MFMAs (resolves to the same vmcnt(8) -> no hidden tighter fence).
// Ledger: at end-of-iter-T vmcnt(8), all ops older than GLL(T+2) landed -> GLL(T+1)
//   landed -> slot (T+1)&3 resident for iter T+1 (block-wide via barrier). WAR:
//   GLL(T+3) writes slot (T-1)&3 whose readers finished before iter T-1's barrier,
//   which precedes this GLL's issue. Prologue: [LDB(0)^4, GLL t0,t1,t2] vmcnt(4) ->
//   B(0)+tile0 landed. Tail: STG(NT-1); TB0; vmcnt(0)+barrier; TB1..TB3 (compiler
//   auto-waits the L2-hot B loads).
// B-frag algebra (stage swz ^ read swz cancel): lane(quad,m16), wave wc, frag nt reads
//   global B[bn + wc*64 + nt*16 + m16][T*32 + quad*8 .. +7] -- one 16B dwordx4/lane,
//   straight to VGPRs, prefetched one K-tile ahead; B-panel L2-hot (reused 32x).
// LDS now A-only (4-slot ring 64KB): 64KB reads + 16KB writes/iter ~= 715 cyc < MFMA
//   1242 cyc -> matrix pipe becomes the binding resource.
// Epilogue: y = sc[m]*(acc - c0f[m]*wc0[n]) + bias[n]; partials part[gm*64 + bxi*4 + wc].
template<int N, int K>
__global__ __launch_bounds__(512, 2) void k_gemm256(
    const unsigned short* __restrict__ A,
    const unsigned short* __restrict__ B,
    const float* __restrict__ bias,
    const float* __restrict__ sc,
    const float* __restrict__ c0f,
    const float* __restrict__ wc0,
    unsigned short* __restrict__ Cb,
    float* __restrict__ part)
{
  static_assert(K % 128 == 0 && K / 32 >= 8, "need NT multiple of 4, >= 8");
  constexpr int NT = K / 32;
  __shared__ __align__(16) unsigned short S[4][8192];   // A-only: [slot][256 x 32]

  const int tid  = threadIdx.x;
  const int wave = tid >> 6;
  const int lane = tid & 63;
  const int quad = lane >> 4;
  const int m16  = lane & 15;
  const int wr   = wave >> 2;     // 0..1 (M half)
  const int wc   = wave & 3;      // 0..3 (N column)

  // bijective XCD swizzle: 512 blocks = 8 XCDs x 64; each XCD gets an 8x8 tile patch
  const int j = blockIdx.x & 7;
  const int k = blockIdx.x >> 3;                 // 0..63
  const int bxi = 8 * (j & 1) + (k & 7);         // 0..15  (N/256)
  const int byi = 8 * (j >> 1) + (k >> 3);       // 0..31  (M/256)
  const int bm = byi * 256;
  const int bn = bxi * 256;

  // A staging: thread -> row tid>>2, LDS granule tid&3; global granule pre-swizzled
  const int gsw8 = (((tid & 3) ^ ((tid >> 3) & 3)) << 3);
  const unsigned short* gAp = A + (size_t)(bm + (tid >> 2)) * K + gsw8;   // rows 0..127
  const unsigned short* gAq = gAp + (size_t)128 * K;                      // rows 128..255
  char* SbW = (char*)&S[0][0];
  const int ldw = wave * 1024;     // wave's 16-row stripe within an 8KB half-region

  // B direct-load lane pointers: row = bn + wc*64 + nt*16 + m16, col granule = quad*8
  const unsigned short* pB0 = B + (size_t)(bn + wc * 64 + m16) * K + quad * 8;
  const unsigned short* pB1 = pB0 + (size_t)16 * K;
  const unsigned short* pB2 = pB0 + (size_t)32 * K;
  const unsigned short* pB3 = pB0 + (size_t)48 * K;

  // A read side: swizzled granule, byte base + compile-time slot/frag immediates
  const int rsw8 = ((quad ^ ((m16 >> 1) & 3)) << 3);
  const char* Ab = (const char*)&S[0][0] + ((wr * 128 + m16) * 32 + rsw8) * 2;

  floatx4 acc[8][4];
#pragma unroll
  for (int i = 0; i < 8; ++i)
#pragma unroll
    for (int jj = 0; jj < 4; ++jj)
#pragma unroll
      for (int r = 0; r < 4; ++r) acc[i][jj][r] = 0.0f;

#define GLL(SRC, DST) __builtin_amdgcn_global_load_lds((gbl_void_t*)(void*)(SRC), (lds_void_t*)(DST), 16, 0, 0)
#define STG(SL, CO) { GLL(gAp + (CO), SbW + (SL) * 16384 + ldw); \
                      GLL(gAq + (CO), SbW + (SL) * 16384 + 8192 + ldw); }
#define LDB(BN, CO) { BN[0] = *(const bf16x8*)(pB0 + (CO)); \
                      BN[1] = *(const bf16x8*)(pB1 + (CO)); \
                      BN[2] = *(const bf16x8*)(pB2 + (CO)); \
                      BN[3] = *(const bf16x8*)(pB3 + (CO)); }
#define ARD(SL, M_) (*(const bf16x8*)(Ab + (SL) * 16384 + (M_) * 1024))

  // prologue: B(0) + stage A tiles 0,1,2; vmcnt(4) -> B(0) and tile 0 landed
  bf16x8 bX[4], bY[4];
  LDB(bX, 0)
  STG(0, 0) STG(1, 32) STG(2, 64)
  asm volatile("s_waitcnt vmcnt(4)" ::: "memory");
  __builtin_amdgcn_s_barrier();

  // main body BI (0..3): tile T=t+BI from slot BI; load B(T+1); stage A(T+3)
#define MBODY(BI, BC, BN)                                                              \
  {                                                                                    \
    LDB(BN, (BI + 1) * 32)                                                             \
    STG((BI + 3) & 3, (BI + 3) * 32)                                                   \
    bf16x8 a_[8];                                                                      \
    _Pragma("unroll")                                                                  \
    for (int m = 0; m < 8; ++m) a_[m] = ARD(BI, m);                                    \
    __builtin_amdgcn_s_setprio(1);                                                     \
    _Pragma("unroll")                                                                  \
    for (int f = 0; f < 8; ++f)                                                        \
      _Pragma("unroll")                                                                \
      for (int n = 0; n < 4; ++n)                                                      \
        acc[f][n] = __builtin_amdgcn_mfma_f32_16x16x32_bf16(a_[f], BC[n], acc[f][n], 0, 0, 0); \
    __builtin_amdgcn_s_setprio(0);                                                     \
    asm volatile("s_waitcnt vmcnt(8)" ::: "memory");                                   \
    __builtin_amdgcn_s_barrier();                                                      \
  }

  for (int t = 0; t < NT - 4; t += 4) {
    MBODY(0, bX, bY)
    MBODY(1, bY, bX)
    MBODY(2, bX, bY)
    MBODY(3, bY, bX)
    gAp += 128; gAq += 128; pB0 += 128; pB1 += 128; pB2 += 128; pB3 += 128;
  }
  // after loop: bX = B(NT-4); pointers at tile NT-4's column; slots 0..3 = NT-4..NT-1

  // tail: stage tile NT-1 (slot 3)
  STG(3, 96)
  // TB0 (tile NT-4, slot 0): consume bX, load bY = B(NT-3)
  {
    LDB(bY, 32)
    bf16x8 a_[8];
#pragma unroll
    for (int m = 0; m < 8; ++m) a_[m] = ARD(0, m);
    __builtin_amdgcn_s_setprio(1);
#pragma unroll
    for (int f = 0; f < 8; ++f)
#pragma unroll
      for (int n = 0; n < 4; ++n)
        acc[f][n] = __builtin_amdgcn_mfma_f32_16x16x32_bf16(a_[f], bX[n], acc[f][n], 0, 0, 0);
    __builtin_amdgcn_s_setprio(0);
  }
  // drain all staging (tiles NT-2, NT-1) block-wide
  asm volatile("s_waitcnt vmcnt(0)" ::: "memory");
  __builtin_amdgcn_s_barrier();
  // TB1 (tile NT-3, slot 1): consume bY, load bX = B(NT-2)
  {
    LDB(bX, 64)
    bf16x8 a_[8];
#pragma unroll
    for (int m = 0; m < 8; ++m) a_[m] = ARD(1, m);
    __builtin_amdgcn_s_setprio(1);
#pragma unroll
    for (int f = 0; f < 8; ++f)
#pragma unroll
      for (int n = 0; n < 4; ++n)
        acc[f][n] = __builtin_amdgcn_mfma_f32_16x16x32_bf16(a_[f], bY[n], acc[f][n], 0, 0, 0);
    __builtin_amdgcn_s_setprio(0);
  }
  // TB2 (tile NT-2, slot 2): consume bX, load bY = B(NT-1)
  {
    LDB(bY, 96)
    bf16x8 a_[8];
#pragma unroll
    for (int m = 0; m < 8; ++m) a_[m] = ARD(2, m);
    __builtin_amdgcn_s_setprio(1);
#pragma unroll
    for (int f = 0; f < 8; ++f)
#pragma unroll
      for (int n = 0; n < 4; ++n)
        acc[f][n] = __builtin_amdgcn_mfma_f32_16x16x32_bf16(a_[f], bX[n], acc[f][n], 0, 0, 0);
    __builtin_amdgcn_s_setprio(0);
  }
  // TB3 (tile NT-1, slot 3): consume bY
  {
    bf16x8 a_[8];
#pragma unroll
    for (int m = 0; m < 8; ++m) a_[m] = ARD(3, m);
    __builtin_amdgcn_s_setprio(1);
#pragma unroll
    for (int f = 0; f < 8; ++f)
#pragma unroll
      for (int n = 0; n < 4; ++n)
        acc[f][n] = __builtin_amdgcn_mfma_f32_16x16x32_bf16(a_[f], bY[n], acc[f][n], 0, 0, 0);
    __builtin_amdgcn_s_setprio(0);
  }

#undef MBODY
#undef ARD
#undef LDB
#undef STG
#undef GLL

  // epilogue: C/D layout col = lane&15, row = quad*4 + r
  const int wm = wr * 128;
  const int wn = wc * 64;
#pragma unroll
  for (int mt = 0; mt < 8; ++mt) {
#pragma unroll
    for (int r = 0; r < 4; ++r) {
      const int gm = bm + wm + mt * 16 + quad * 4 + r;
      const float scv = sc[gm];
      const float c0v = c0f[gm];
      float sq = 0.f;
#pragma unroll
      for (int nt = 0; nt < 4; ++nt) {
        const int gn = bn + wn + nt * 16 + m16;
        float v = scv * (acc[mt][nt][r] - c0v * wc0[gn]) + bias[gn];
        Cb[(size_t)gm * N + gn] = f2bf(v);
        sq += (gn == 0) ? 0.f : v * v;
      }
      sq += __shfl_xor(sq, 1, 64);
      sq += __shfl_xor(sq, 2, 64);
      sq += __shfl_xor(sq, 4, 64);
      sq += __shfl_xor(sq, 8, 64);
      if (m16 == 0) part[(size_t)gm * 64 + bxi * 4 + wc] = sq;
    }
  }
}

extern "C" void kernel_launch(void* const* d_in, const int* in_sizes, int n_in,
                              void* d_out, int out_size, void* d_ws, size_t ws_size,
                              hipStream_t stream) {
  const void* x  = d_in[0];
  const void* W1 = d_in[1];
  const void* b1 = d_in[2];
  const void* W2 = d_in[3];
  const void* b2 = d_in[4];
  const void* W3 = d_in[5];
  const void* b3 = d_in[6];

  const int NR = 8192, DIN = 1024, DH = 4096, DOUT = 1024;

  char* ws = (char*)d_ws;
  size_t off = 0;
  int* mode = (int*)(ws + off);                        off += 256;
  unsigned short* W1b = (unsigned short*)(ws + off);   off += (size_t)DH * DIN * 2;
  unsigned short* W2b = (unsigned short*)(ws + off);   off += (size_t)DH * DH * 2;
  unsigned short* W3b = (unsigned short*)(ws + off);   off += (size_t)DOUT * DH * 2;
  unsigned short* xb  = (unsigned short*)(ws + off);   off += (size_t)NR * DIN * 2;
  unsigned short* y1  = (unsigned short*)(ws + off);   off += (size_t)NR * DH * 2;
  unsigned short* y2  = (unsigned short*)(ws + off);   off += (size_t)NR * DH * 2;
  unsigned short* y3  = (unsigned short*)(ws + off);   off += (size_t)NR * DOUT * 2;
  float* part1 = (float*)(ws + off);                   off += (size_t)NR * 64 * 4;
  float* part2 = (float*)(ws + off);                   off += (size_t)NR * 64 * 4;
  float* part3 = (float*)(ws + off);                   off += (size_t)NR * 16 * 4;
  float* sc0  = (float*)(ws + off);                    off += (size_t)NR * 4;
  float* x0c  = (float*)(ws + off);                    off += (size_t)NR * 4;
  float* sc1  = (float*)(ws + off);                    off += (size_t)NR * 4;
  float* c01  = (float*)(ws + off);                    off += (size_t)NR * 4;
  float* sc2  = (float*)(ws + off);                    off += (size_t)NR * 4;
  float* c02  = (float*)(ws + off);                    off += (size_t)NR * 4;
  float* ss3  = (float*)(ws + off);                    off += (size_t)NR * 4;
  float* w1c0 = (float*)(ws + off);                    off += (size_t)DH * 4;
  float* w2c0 = (float*)(ws + off);                    off += (size_t)DH * 4;
  float* w3c0 = (float*)(ws + off);                    off += (size_t)DOUT * 4;
  float* b1f  = (float*)(ws + off);                    off += (size_t)DH * 4;
  float* b2f  = (float*)(ws + off);                    off += (size_t)DH * 4;
  float* b3f  = (float*)(ws + off);                    off += (size_t)DOUT * 4;

  k_init<<<16, 256, 0, stream>>>((const unsigned short*)x, mode, b1, b2, b3, b1f, b2f, b3f);

  k_cvtw<128><<<(DH * DIN / 8 + 255) / 256, 256, 0, stream>>>(W1, W1b, mode, DH * DIN / 8, w1c0);
  k_cvtw<512><<<(DH * DH  / 8 + 255) / 256, 256, 0, stream>>>(W2, W2b, mode, DH * DH / 8, w2c0);
  k_cvtw<512><<<(DOUT * DH / 8 + 255) / 256, 256, 0, stream>>>(W3, W3b, mode, DOUT * DH / 8, w3c0);

  k_prep<<<NR, 256, 0, stream>>>(x, xb, sc0, x0c, mode);

  k_gemm256<4096, 1024><<<512, 512, 0, stream>>>(
      xb, W1b, b1f, sc0, x0c, w1c0, y1, part1);
  k_sc<64><<<(NR + 255) / 256, 256, 0, stream>>>(part1, y1, DH, sc1, c01, nullptr, NR);

  k_gemm256<4096, 4096><<<512, 512, 0, stream>>>(
      y1, W2b, b2f, sc1, c01, w2c0, y2, part2);
  k_sc<64><<<(NR + 255) / 256, 256, 0, stream>>>(part2, y2, DH, sc2, c02, nullptr, NR);

  k_gemm_bt<1024, 4096, 16, 8><<<512, 256, 0, stream>>>(
      y2, W3b, b3f, sc2, c02, w3c0, y3, part3);
  k_sc<16><<<(NR + 255) / 256, 256, 0, stream>>>(part3, y3, DOUT, sc0, x0c, ss3, NR);

  k_final<<<NR, 256, 0, stream>>>(y3, ss3, d_out, mode);
}

// Round 11
// 614.957 us; speedup vs baseline: 1.1945x; 1.1829x over previous
//
#include <hip/hip_runtime.h>
#include <stdint.h>

#define EPSF 1e-7f
#define MAXTAN 10.0f

typedef __bf16 bf16x8 __attribute__((ext_vector_type(8)));
typedef float floatx4 __attribute__((ext_vector_type(4)));
typedef __attribute__((address_space(3))) void lds_void_t;
typedef __attribute__((address_space(1))) void gbl_void_t;

__device__ __forceinline__ unsigned short f2bf(float x) {
  union { float f; uint32_t u; } v; v.f = x;
  uint32_t u = v.u;
  u += 0x7fffu + ((u >> 16) & 1u);   // RNE
  return (unsigned short)(u >> 16);
}
__device__ __forceinline__ float bf2f(unsigned short h) {
  union { uint32_t u; float f; } v; v.u = ((uint32_t)h) << 16;
  return v.f;
}

__device__ __forceinline__ int sniff_mode(const unsigned short* x) {
  int sane = 0;
  for (int i = 0; i < 128; ++i) {
    unsigned short h = x[i];
    int e = (h >> 7) & 0xFF;
    if ((h & 0x7FFF) == 0 || (e >= 96 && e <= 140)) ++sane;
  }
  return (sane >= 120) ? 1 : 0;
}

// ---------------- fused pre-pass bodies ----------------
template<int K8>
__device__ __forceinline__ void cvtw_body(const void* __restrict__ in,
                                          unsigned short* __restrict__ out,
                                          int m, int blk, int n8,
                                          float* __restrict__ c0) {
  int i = blk * 256 + threadIdx.x;
  if (i >= n8) return;
  if (m) {
    uint4 g = ((const uint4*)in)[i];
    ((uint4*)out)[i] = g;
    if (i % K8 == 0) c0[i / K8] = bf2f((unsigned short)(g.x & 0xFFFFu));
  } else {
    float4 a = ((const float4*)in)[2 * i];
    float4 b = ((const float4*)in)[2 * i + 1];
    ushort4 oa, ob;
    oa.x = f2bf(a.x); oa.y = f2bf(a.y); oa.z = f2bf(a.z); oa.w = f2bf(a.w);
    ob.x = f2bf(b.x); ob.y = f2bf(b.y); ob.z = f2bf(b.z); ob.w = f2bf(b.w);
    ((ushort4*)out)[2 * i] = oa;
    ((ushort4*)out)[2 * i + 1] = ob;
    if (i % K8 == 0) c0[i / K8] = bf2f(oa.x);
  }
}

__device__ __forceinline__ void prep_body(const void* __restrict__ xv,
                                          unsigned short* __restrict__ xb,
                                          float* __restrict__ sc0,
                                          float* __restrict__ x0c,
                                          int m, int row, float* red) {
  const int tid = threadIdx.x;
  float4 v;
  if (m) {
    ushort4 u = ((const ushort4*)((const unsigned short*)xv + (size_t)row * 1024))[tid];
    v.x = bf2f(u.x); v.y = bf2f(u.y); v.z = bf2f(u.z); v.w = bf2f(u.w);
  } else {
    v = ((const float4*)((const float*)xv + (size_t)row * 1024))[tid];
  }
  ushort4 o;
  o.x = f2bf(v.x); o.y = f2bf(v.y); o.z = f2bf(v.z); o.w = f2bf(v.w);
  ((ushort4*)(xb + (size_t)row * 1024))[tid] = o;

  float s = v.x * v.x + v.y * v.y + v.z * v.z + v.w * v.w;
  if (tid == 0) s -= v.x * v.x;          // exclude time coordinate
  for (int off = 32; off; off >>= 1) s += __shfl_down(s, off, 64);
  if ((tid & 63) == 0) red[tid >> 6] = s;
  __syncthreads();
  if (tid == 0) {
    s = red[0] + red[1] + red[2] + red[3];
    float ns = fmaxf(sqrtf(s), EPSF);
    float d = acoshf(fmaxf(v.x, 1.0f + EPSF));
    sc0[row] = d / ns;
    x0c[row] = bf2f(o.x);
  }
}

// ---------------- k_pre: fused init + W1/W2/W3 convert + x prep + biases ----------------
// Single launch replacing 5 serial launches. Every block sniffs dtype locally
// (x[0..127] = 256B, L2-broadcast -> trivial); roles are independent, so small
// roles hide under big ones across CUs instead of serializing.
// Roles by blockIdx: [0,2048) W1 | [2048,10240) W2 | [10240,12288) W3 |
//                    [12288,20480) prep rows | [20480,20496) biases + mode write.
__global__ void k_pre(const unsigned short* __restrict__ x, int* __restrict__ modeg,
                      const void* __restrict__ W1, const void* __restrict__ W2,
                      const void* __restrict__ W3,
                      const void* __restrict__ b1, const void* __restrict__ b2,
                      const void* __restrict__ b3,
                      unsigned short* __restrict__ W1b, unsigned short* __restrict__ W2b,
                      unsigned short* __restrict__ W3b,
                      unsigned short* __restrict__ xb, float* __restrict__ sc0,
                      float* __restrict__ x0c,
                      float* __restrict__ w1c0, float* __restrict__ w2c0,
                      float* __restrict__ w3c0,
                      float* __restrict__ b1f, float* __restrict__ b2f,
                      float* __restrict__ b3f) {
  __shared__ int mds;
  __shared__ float red[4];
  if (threadIdx.x == 0) mds = sniff_mode(x);
  __syncthreads();
  const int m = mds;
  int b = blockIdx.x;
  if (b < 2048) { cvtw_body<128>(W1, W1b, m, b, 4096 * 1024 / 8, w1c0); return; }
  b -= 2048;
  if (b < 8192) { cvtw_body<512>(W2, W2b, m, b, 4096 * 4096 / 8, w2c0); return; }
  b -= 8192;
  if (b < 2048) { cvtw_body<512>(W3, W3b, m, b, 1024 * 4096 / 8, w3c0); return; }
  b -= 2048;
  if (b < 8192) { prep_body(x, xb, sc0, x0c, m, b, red); return; }
  b -= 8192;
  // bias role (16 blocks)
  if (b == 0 && threadIdx.x == 0) *modeg = m;
  int i = b * 256 + threadIdx.x;
  if (i < 4096) b1f[i] = m ? bf2f(((const unsigned short*)b1)[i]) : ((const float*)b1)[i];
  if (i < 4096) b2f[i] = m ? bf2f(((const unsigned short*)b2)[i]) : ((const float*)b2)[i];
  if (i < 1024) b3f[i] = m ? bf2f(((const unsigned short*)b3)[i]) : ((const float*)b3)[i];
}

// ---------------- partial-sumsq fold -> scale + col0 grab ----------------
template<int NBLK>
__global__ void k_sc(const float* __restrict__ part, const unsigned short* __restrict__ y,
                     int stride, float* __restrict__ sc, float* __restrict__ c0,
                     float* __restrict__ ssout, int nrows) {
  int i = blockIdx.x * 256 + threadIdx.x;
  if (i >= nrows) return;
  float s = 0.f;
#pragma unroll
  for (int j = 0; j < NBLK; ++j) s += part[(size_t)i * NBLK + j];
  float n = fmaxf(sqrtf(fmaxf(s, 0.f)), EPSF);
  sc[i] = fminf(n, MAXTAN) / n;
  c0[i] = bf2f(y[(size_t)i * stride]);
  if (ssout) ssout[i] = s;
}

// ---------------- final: y3 bf16 + ss3 -> projx(safe_expmap0(y3)) ----------------
__global__ void k_final(const unsigned short* __restrict__ y, const float* __restrict__ ss,
                        void* __restrict__ outv, const int* __restrict__ mode) {
  const int row = blockIdx.x;
  const int tid = threadIdx.x;
  float n = fmaxf(sqrtf(fmaxf(ss[row], 0.f)), EPSF);
  float nc = fminf(n, MAXTAN);
  float a = sinhf(nc) / n;
  ushort4 u = ((const ushort4*)(y + (size_t)row * 1024))[tid];
  float4 o;
  o.x = bf2f(u.x) * a; o.y = bf2f(u.y) * a;
  o.z = bf2f(u.z) * a; o.w = bf2f(u.w) * a;
  if (tid == 0) o.x = coshf(nc);
  if (*mode) {
    ushort4 o16;
    o16.x = f2bf(o.x); o16.y = f2bf(o.y); o16.z = f2bf(o.z); o16.w = f2bf(o.w);
    ((ushort4*)outv)[(size_t)row * 256 + tid] = o16;
  } else {
    ((float4*)outv)[(size_t)row * 256 + tid] = o;
  }
}

// ---------------- legacy 128x128 NT GEMM (kept for GEMM3) ----------------
template<int N, int K, int NBLK, int GX>
__global__ __launch_bounds__(256, 4) void k_gemm_bt(
    const unsigned short* __restrict__ A,
    const unsigned short* __restrict__ B,
    const float* __restrict__ bias,
    const float* __restrict__ sc,
    const float* __restrict__ c0f,
    const float* __restrict__ wc0,
    unsigned short* __restrict__ Cb,
    float* __restrict__ part)
{
  __shared__ __align__(16) unsigned short As[128 * 32];
  __shared__ __align__(16) unsigned short Bs[128 * 32];

  const int tid  = threadIdx.x;
  const int wave = tid >> 6;
  const int lane = tid & 63;
  const int quad = lane >> 4;
  const int m16  = lane & 15;

  const int j = blockIdx.x & 7;
  const int k = blockIdx.x >> 3;
  int bxi, byi;
  if (GX == 32) {
    bxi = 16 * (j & 1) + (k & 15);
    byi = 16 * (j >> 1) + (k >> 4);
  } else {
    bxi = k & 7;
    byi = 8 * j + (k >> 3);
  }
  const int bm = byi * 128;
  const int bn = bxi * 128;

  const int srow = lane >> 2;
  const int scol = (((lane & 3) ^ ((srow >> 1) & 3)) << 3);

  const int wm = (wave >> 1) << 6;
  const int wn = (wave & 1) << 6;

  const int rsw = ((quad ^ ((m16 >> 1) & 3)) << 3);

  const int c0i = wave * 2;
  const unsigned short* ga0 = A + (size_t)(bm + c0i * 16 + srow) * K + scol;
  const unsigned short* ga1 = ga0 + (size_t)16 * K;
  const unsigned short* gb0 = B + (size_t)(bn + c0i * 16 + srow) * K + scol;
  const unsigned short* gb1 = gb0 + (size_t)16 * K;

  floatx4 acc[4][4];
#pragma unroll
  for (int i = 0; i < 4; ++i)
#pragma unroll
    for (int jj = 0; jj < 4; ++jj)
#pragma unroll
      for (int r = 0; r < 4; ++r) acc[i][jj][r] = 0.0f;

  for (int k0 = 0; k0 < K; k0 += 32) {
    __builtin_amdgcn_global_load_lds((gbl_void_t*)(void*)ga0,
                                     (lds_void_t*)(As + c0i * 512), 16, 0, 0);
    __builtin_amdgcn_global_load_lds((gbl_void_t*)(void*)ga1,
                                     (lds_void_t*)(As + c0i * 512 + 512), 16, 0, 0);
    __builtin_amdgcn_global_load_lds((gbl_void_t*)(void*)gb0,
                                     (lds_void_t*)(Bs + c0i * 512), 16, 0, 0);
    __builtin_amdgcn_global_load_lds((gbl_void_t*)(void*)gb1,
                                     (lds_void_t*)(Bs + c0i * 512 + 512), 16, 0, 0);
    ga0 += 32; ga1 += 32; gb0 += 32; gb1 += 32;
    __syncthreads();

    bf16x8 af[4], bfg[4];
#pragma unroll
    for (int t = 0; t < 4; ++t) {
      af[t]  = *(const bf16x8*)(As + (wm + t * 16 + m16) * 32 + rsw);
      bfg[t] = *(const bf16x8*)(Bs + (wn + t * 16 + m16) * 32 + rsw);
    }
#pragma unroll
    for (int mt = 0; mt < 4; ++mt)
#pragma unroll
      for (int nt = 0; nt < 4; ++nt)
        acc[mt][nt] = __builtin_amdgcn_mfma_f32_16x16x32_bf16(af[mt], bfg[nt], acc[mt][nt], 0, 0, 0);
    __syncthreads();
  }

#pragma unroll
  for (int mt = 0; mt < 4; ++mt) {
#pragma unroll
    for (int r = 0; r < 4; ++r) {
      const int gm = bm + wm + mt * 16 + quad * 4 + r;
      const float scv = sc[gm];
      const float c0v = c0f[gm];
      float sq = 0.f;
#pragma unroll
      for (int nt = 0; nt < 4; ++nt) {
        const int gn = bn + wn + nt * 16 + m16;
        float v = scv * (acc[mt][nt][r] - c0v * wc0[gn]) + bias[gn];
        Cb[(size_t)gm * N + gn] = f2bf(v);
        sq += (gn == 0) ? 0.f : v * v;
      }
      sq += __shfl_xor(sq, 1, 64);
      sq += __shfl_xor(sq, 2, 64);
      sq += __shfl_xor(sq, 4, 64);
      sq += __shfl_xor(sq, 8, 64);
      if (m16 == 0) part[(size_t)gm * NBLK + 2 * bxi + (wave & 1)] = sq;
    }
  }
}

// ---------------- 256x256 NT GEMM, lean 4x-unrolled pipeline (R6 -- session best) ----------------
// R9/R10's B-direct variant refuted (29% MfmaUtil both at vmcnt(2) and vmcnt(8));
// reverted to the verified R6 structure: A+B in a 4-slot LDS ring (128KB), x4-unrolled
// main loop with compile-time slots, B-side one-tile-ahead register pre-read, peeled
// stage-free tail. Measured (R6): GEMM2 239.6us, MfmaUtil 53.4%, 0 bank conflicts.
template<int N, int K>
__global__ __launch_bounds__(512, 2) void k_gemm256(
    const unsigned short* __restrict__ A,
    const unsigned short* __restrict__ B,
    const float* __restrict__ bias,
    const float* __restrict__ sc,
    const float* __restrict__ c0f,
    const float* __restrict__ wc0,
    unsigned short* __restrict__ Cb,
    float* __restrict__ part)
{
  static_assert(K % 128 == 0 && K / 32 >= 8, "need NT multiple of 4, >= 8");
  constexpr int NT = K / 32;
  __shared__ __align__(16) unsigned short S[4][2][8192];   // [slot][A/B][256*32]

  const int tid  = threadIdx.x;
  const int wave = tid >> 6;
  const int lane = tid & 63;
  const int quad = lane >> 4;
  const int m16  = lane & 15;
  const int wr   = wave >> 2;     // 0..1 (M)
  const int wc   = wave & 3;      // 0..3 (N)

  // bijective XCD swizzle: 512 blocks = 8 XCDs x 64; each XCD gets an 8x8 tile patch
  const int j = blockIdx.x & 7;
  const int k = blockIdx.x >> 3;                 // 0..63
  const int bxi = 8 * (j & 1) + (k & 7);         // 0..15  (N/256)
  const int byi = 8 * (j >> 1) + (k >> 3);       // 0..31  (M/256)
  const int bm = byi * 256;
  const int bn = bxi * 256;

  // staging: thread -> row tid>>2, LDS granule tid&3; global granule pre-swizzled
  const int gsw8 = (((tid & 3) ^ ((tid >> 3) & 3)) << 3);
  const unsigned short* gAp = A + (size_t)(bm + (tid >> 2)) * K + gsw8;
  const unsigned short* gAq = gAp + (size_t)128 * K;
  const unsigned short* gBp = B + (size_t)(bn + (tid >> 2)) * K + gsw8;
  const unsigned short* gBq = gBp + (size_t)128 * K;
  const int ldw = wave * 1024;         // byte offset of this wave's 16-row stripe

  // read-side swizzle + byte-base pointers (compile-time immediates per slot/frag)
  const int rsw8 = ((quad ^ ((m16 >> 1) & 3)) << 3);
  const int aoffB = ((wr * 128 + m16) * 32 + rsw8) * 2;
  const int boffB = ((wc * 64  + m16) * 32 + rsw8) * 2;
  const char* Sb  = (const char*)&S[0][0][0];
  const char* pA  = Sb + aoffB;                  // A slots 0,1
  const char* pA2 = pA + 65536;                  // A slots 2,3
  const char* pB  = Sb + 16384 + boffB;          // B slots 0,1
  const char* pB2 = pB + 65536;                  // B slots 2,3

  floatx4 acc[8][4];
#pragma unroll
  for (int i = 0; i < 8; ++i)
#pragma unroll
    for (int jj = 0; jj < 4; ++jj)
#pragma unroll
      for (int r = 0; r < 4; ++r) acc[i][jj][r] = 0.0f;

#define GLL(SRC, DST) __builtin_amdgcn_global_load_lds((gbl_void_t*)(void*)(SRC), (lds_void_t*)(DST), 16, 0, 0)
#define ARD(S_, M_) (*(const bf16x8*)(((S_) < 2 ? pA : pA2) + ((S_) * 32768 + (M_) * 1024 - ((S_) < 2 ? 0 : 65536))))
#define BRD(S_, N_) (*(const bf16x8*)(((S_) < 2 ? pB : pB2) + ((S_) * 32768 + (N_) * 1024 - ((S_) < 2 ? 0 : 65536))))
#define STG(T_, OFF) { \
    GLL(gAp + (OFF), (char*)Sb + (T_) * 32768 +         ldw); \
    GLL(gAq + (OFF), (char*)Sb + (T_) * 32768 +  8192 + ldw); \
    GLL(gBp + (OFF), (char*)Sb + (T_) * 32768 + 16384 + ldw); \
    GLL(gBq + (OFF), (char*)Sb + (T_) * 32768 + 24576 + ldw); }

  // prologue: stage tiles 0,1,2; vmcnt(4) -> tiles 0,1 resident
  STG(0, 0) STG(1, 32) STG(2, 64)
  asm volatile("s_waitcnt vmcnt(4)" ::: "memory");
  __builtin_amdgcn_s_barrier();

  bf16x8 bX[4], bY[4];
#pragma unroll
  for (int n = 0; n < 4; ++n) bX[n] = BRD(0, n);   // pre-read b(0)

#define MBODY(BI, BC, BN)                                                              \
  {                                                                                    \
    STG((BI + 3) & 3, (BI + 3) * 32)                                                   \
    bf16x8 a_[8];                                                                      \
    _Pragma("unroll")                                                                  \
    for (int m = 0; m < 8; ++m) a_[m] = ARD(BI, m);                                    \
    __builtin_amdgcn_s_setprio(1);                                                     \
    _Pragma("unroll")                                                                  \
    for (int f = 0; f < 4; ++f)                                                        \
      _Pragma("unroll")                                                                \
      for (int n = 0; n < 4; ++n)                                                      \
        acc[f][n] = __builtin_amdgcn_mfma_f32_16x16x32_bf16(a_[f], BC[n], acc[f][n], 0, 0, 0); \
    __builtin_amdgcn_s_setprio(0);                                                     \
    _Pragma("unroll")                                                                  \
    for (int n = 0; n < 4; ++n) BN[n] = BRD((BI + 1) & 3, n);                          \
    __builtin_amdgcn_s_setprio(1);                                                     \
    _Pragma("unroll")                                                                  \
    for (int f = 0; f < 4; ++f)                                                        \
      _Pragma("unroll")                                                                \
      for (int n = 0; n < 4; ++n)                                                      \
        acc[f + 4][n] = __builtin_amdgcn_mfma_f32_16x16x32_bf16(a_[f + 4], BC[n], acc[f + 4][n], 0, 0, 0); \
    __builtin_amdgcn_s_setprio(0);                                                     \
    asm volatile("s_waitcnt vmcnt(4)" ::: "memory");                                   \
    __builtin_amdgcn_s_barrier();                                                      \
  }

  for (int t = 0; t < NT - 4; t += 4) {
    MBODY(0, bX, bY)
    MBODY(1, bY, bX)
    MBODY(2, bX, bY)
    MBODY(3, bY, bX)
    gAp += 128; gAq += 128; gBp += 128; gBq += 128;
  }

  // tail: tiles NT-4..NT-1 in slots 0..3. Stage tile NT-1 (slot 3; col offset 96).
  STG(3, 96)
  // TB0 (tile NT-4, slot 0): consume bX, preload bY=b(NT-3)
  {
    bf16x8 a_[8];
#pragma unroll
    for (int m = 0; m < 8; ++m) a_[m] = ARD(0, m);
    __builtin_amdgcn_s_setprio(1);
#pragma unroll
    for (int f = 0; f < 4; ++f)
#pragma unroll
      for (int n = 0; n < 4; ++n)
        acc[f][n] = __builtin_amdgcn_mfma_f32_16x16x32_bf16(a_[f], bX[n], acc[f][n], 0, 0, 0);
    __builtin_amdgcn_s_setprio(0);
#pragma unroll
    for (int n = 0; n < 4; ++n) bY[n] = BRD(1, n);
    __builtin_amdgcn_s_setprio(1);
#pragma unroll
    for (int f = 0; f < 4; ++f)
#pragma unroll
      for (int n = 0; n < 4; ++n)
        acc[f + 4][n] = __builtin_amdgcn_mfma_f32_16x16x32_bf16(a_[f + 4], bX[n], acc[f + 4][n], 0, 0, 0);
    __builtin_amdgcn_s_setprio(0);
  }
  asm volatile("s_waitcnt vmcnt(0)" ::: "memory");
  __builtin_amdgcn_s_barrier();
  // TB1 (tile NT-3, slot 1): consume bY, preload bX=b(NT-2)
  {
    bf16x8 a_[8];
#pragma unroll
    for (int m = 0; m < 8; ++m) a_[m] = ARD(1, m);
    __builtin_amdgcn_s_setprio(1);
#pragma unroll
    for (int f = 0; f < 4; ++f)
#pragma unroll
      for (int n = 0; n < 4; ++n)
        acc[f][n] = __builtin_amdgcn_mfma_f32_16x16x32_bf16(a_[f], bY[n], acc[f][n], 0, 0, 0);
    __builtin_amdgcn_s_setprio(0);
#pragma unroll
    for (int n = 0; n < 4; ++n) bX[n] = BRD(2, n);
    __builtin_amdgcn_s_setprio(1);
#pragma unroll
    for (int f = 0; f < 4; ++f)
#pragma unroll
      for (int n = 0; n < 4; ++n)
        acc[f + 4][n] = __builtin_amdgcn_mfma_f32_16x16x32_bf16(a_[f + 4], bY[n], acc[f + 4][n], 0, 0, 0);
    __builtin_amdgcn_s_setprio(0);
  }
  // TB2 (tile NT-2, slot 2): consume bX, preload bY=b(NT-1)
  {
    bf16x8 a_[8];
#pragma unroll
    for (int m = 0; m < 8; ++m) a_[m] = ARD(2, m);
    __builtin_amdgcn_s_setprio(1);
#pragma unroll
    for (int f = 0; f < 4; ++f)
#pragma unroll
      for (int n = 0; n < 4; ++n)
        acc[f][n] = __builtin_amdgcn_mfma_f32_16x16x32_bf16(a_[f], bX[n], acc[f][n], 0, 0, 0);
    __builtin_amdgcn_s_setprio(0);
#pragma unroll
    for (int n = 0; n < 4; ++n) bY[n] = BRD(3, n);
    __builtin_amdgcn_s_setprio(1);
#pragma unroll
    for (int f = 0; f < 4; ++f)
#pragma unroll
      for (int n = 0; n < 4; ++n)
        acc[f + 4][n] = __builtin_amdgcn_mfma_f32_16x16x32_bf16(a_[f + 4], bX[n], acc[f + 4][n], 0, 0, 0);
    __builtin_amdgcn_s_setprio(0);
  }
  // TB3 (tile NT-1, slot 3): consume bY
  {
    bf16x8 a_[8];
#pragma unroll
    for (int m = 0; m < 8; ++m) a_[m] = ARD(3, m);
    __builtin_amdgcn_s_setprio(1);
#pragma unroll
    for (int f = 0; f < 4; ++f)
#pragma unroll
      for (int n = 0; n < 4; ++n)
        acc[f][n] = __builtin_amdgcn_mfma_f32_16x16x32_bf16(a_[f], bY[n], acc[f][n], 0, 0, 0);
#pragma unroll
    for (int f = 0; f < 4; ++f)
#pragma unroll
      for (int n = 0; n < 4; ++n)
        acc[f + 4][n] = __builtin_amdgcn_mfma_f32_16x16x32_bf16(a_[f + 4], bY[n], acc[f + 4][n], 0, 0, 0);
    __builtin_amdgcn_s_setprio(0);
  }

#undef MBODY
#undef STG
#undef BRD
#undef ARD
#undef GLL

  // epilogue: C/D layout col = lane&15, row = quad*4 + r
  const int wm = wr * 128;
  const int wn = wc * 64;
#pragma unroll
  for (int mt = 0; mt < 8; ++mt) {
#pragma unroll
    for (int r = 0; r < 4; ++r) {
      const int gm = bm + wm + mt * 16 + quad * 4 + r;
      const float scv = sc[gm];
      const float c0v = c0f[gm];
      float sq = 0.f;
#pragma unroll
      for (int nt = 0; nt < 4; ++nt) {
        const int gn = bn + wn + nt * 16 + m16;
        float v = scv * (acc[mt][nt][r] - c0v * wc0[gn]) + bias[gn];
        Cb[(size_t)gm * N + gn] = f2bf(v);
        sq += (gn == 0) ? 0.f : v * v;
      }
      sq += __shfl_xor(sq, 1, 64);
      sq += __shfl_xor(sq, 2, 64);
      sq += __shfl_xor(sq, 4, 64);
      sq += __shfl_xor(sq, 8, 64);
      if (m16 == 0) part[(size_t)gm * 64 + bxi * 4 + wc] = sq;
    }
  }
}

extern "C" void kernel_launch(void* const* d_in, const int* in_sizes, int n_in,
                              void* d_out, int out_size, void* d_ws, size_t ws_size,
                              hipStream_t stream) {
  const void* x  = d_in[0];
  const void* W1 = d_in[1];
  const void* b1 = d_in[2];
  const void* W2 = d_in[3];
  const void* b2 = d_in[4];
  const void* W3 = d_in[5];
  const void* b3 = d_in[6];

  const int NR = 8192, DIN = 1024, DH = 4096, DOUT = 1024;

  char* ws = (char*)d_ws;
  size_t off = 0;
  int* mode = (int*)(ws + off);                        off += 256;
  unsigned short* W1b = (unsigned short*)(ws + off);   off += (size_t)DH * DIN * 2;
  unsigned short* W2b = (unsigned short*)(ws + off);   off += (size_t)DH * DH * 2;
  unsigned short* W3b = (unsigned short*)(ws + off);   off += (size_t)DOUT * DH * 2;
  unsigned short* xb  = (unsigned short*)(ws + off);   off += (size_t)NR * DIN * 2;
  unsigned short* y1  = (unsigned short*)(ws + off);   off += (size_t)NR * DH * 2;
  unsigned short* y2  = (unsigned short*)(ws + off);   off += (size_t)NR * DH * 2;
  unsigned short* y3  = (unsigned short*)(ws + off);   off += (size_t)NR * DOUT * 2;
  float* part1 = (float*)(ws + off);                   off += (size_t)NR * 64 * 4;
  float* part2 = (float*)(ws + off);                   off += (size_t)NR * 64 * 4;
  float* part3 = (float*)(ws + off);                   off += (size_t)NR * 16 * 4;
  float* sc0  = (float*)(ws + off);                    off += (size_t)NR * 4;
  float* x0c  = (float*)(ws + off);                    off += (size_t)NR * 4;
  float* sc1  = (float*)(ws + off);                    off += (size_t)NR * 4;
  float* c01  = (float*)(ws + off);                    off += (size_t)NR * 4;
  float* sc2  = (float*)(ws + off);                    off += (size_t)NR * 4;
  float* c02  = (float*)(ws + off);                    off += (size_t)NR * 4;
  float* ss3  = (float*)(ws + off);                    off += (size_t)NR * 4;
  float* w1c0 = (float*)(ws + off);                    off += (size_t)DH * 4;
  float* w2c0 = (float*)(ws + off);                    off += (size_t)DH * 4;
  float* w3c0 = (float*)(ws + off);                    off += (size_t)DOUT * 4;
  float* b1f  = (float*)(ws + off);                    off += (size_t)DH * 4;
  float* b2f  = (float*)(ws + off);                    off += (size_t)DH * 4;
  float* b3f  = (float*)(ws + off);                    off += (size_t)DOUT * 4;

  // fused pre-pass: 2048(W1) + 8192(W2) + 2048(W3) + 8192(prep) + 16(bias) blocks
  k_pre<<<20496, 256, 0, stream>>>((const unsigned short*)x, mode, W1, W2, W3,
                                   b1, b2, b3, W1b, W2b, W3b, xb, sc0, x0c,
                                   w1c0, w2c0, w3c0, b1f, b2f, b3f);

  k_gemm256<4096, 1024><<<512, 512, 0, stream>>>(
      xb, W1b, b1f, sc0, x0c, w1c0, y1, part1);
  k_sc<64><<<(NR + 255) / 256, 256, 0, stream>>>(part1, y1, DH, sc1, c01, nullptr, NR);

  k_gemm256<4096, 4096><<<512, 512, 0, stream>>>(
      y1, W2b, b2f, sc1, c01, w2c0, y2, part2);
  k_sc<64><<<(NR + 255) / 256, 256, 0, stream>>>(part2, y2, DH, sc2, c02, nullptr, NR);

  k_gemm_bt<1024, 4096, 16, 8><<<512, 256, 0, stream>>>(
      y2, W3b, b3f, sc2, c02, w3c0, y3, part3);
  k_sc<16><<<(NR + 255) / 256, 256, 0, stream>>>(part3, y3, DOUT, sc0, x0c, ss3, NR);

  k_final<<<NR, 256, 0, stream>>>(y3, ss3, d_out, mode);
}